// Round 6
// baseline (321.814 us; speedup 1.0000x reference)
//
#include <hip/hip_runtime.h>
#include <cstdint>

// PointTransformerLayer, MI355X. Folded-weight formulation:
//   M  = Wt2@Wt1 (64x3)          delta = relu(M . rel)
//   G  = Wg2@Wg1 (64x64)         g = relu(Gphi[n] - Gpsi[idx] + G.delta)
//   wcomb rows: [0:64)=G@W1 (phi), [64:128)=G@W2 (psi), [128:192)=Wlin (alpha)
// R18: knn v7c — insert chain in PURE C (no inline asm in hot loop).
//   Evidence: time == static_VALU x 2.2 across R14/15/16; R17 (launch
//   bounds) was a no-op => not occupancy. The unmodeled ~70 slots/iter
//   scale with the # of asm med3 calls: each "=v" asm output defeats
//   register coalescing into arr's home regs => ~2 v_mov per med3.
//   Sorted-ascending invariant makes med3(key,a[i-1],a[i]) ==
//   min(max(key,a[i-1]),a[i]) (clamp), which LLVM fuses back into
//   v_med3_u32 WITH full regalloc visibility (performMinMaxCombine).
// R16: QW=4 — amortize each candidate ds_read over 4 queries/wave.
// R12: feat_k MFMA GEMM ([192x64]@[64x32768], fused fp32/bf16 epilogue).

#define NPT 8192
typedef unsigned long long u64;
typedef unsigned int u32;
typedef unsigned short u16;
typedef __attribute__((ext_vector_type(8))) short bf8_t;  // 8 bf16 (4 VGPR)
typedef __attribute__((ext_vector_type(4))) float f32x4;

__device__ __forceinline__ u16 f2bf(float x) {  // round-half-up bf16
  return (u16)((__float_as_uint(x) + 0x8000u) >> 16);
}
__device__ __forceinline__ u32 pkbf(float lo, float hi) {
  return (u32)f2bf(lo) | ((u32)f2bf(hi) << 16);
}
__device__ __forceinline__ float bf2f(u16 v) {
  return __uint_as_float((u32)v << 16);
}
__device__ __forceinline__ u32 umin2(u32 a, u32 b) { return a < b ? a : b; }
__device__ __forceinline__ u32 umax2(u32 a, u32 b) { return a > b ? a : b; }
__device__ __forceinline__ float rfl_f(float x) {  // wave-uniform -> SGPR
  return __uint_as_float((u32)__builtin_amdgcn_readfirstlane((int)__float_as_uint(x)));
}
// full-wave u32 min via DPP (VALU pipe); uniform result via readlane.
__device__ __forceinline__ u32 wave_min_u32(u32 v) {
  u32 t;
  t = (u32)__builtin_amdgcn_update_dpp((int)v, (int)v, 0x111, 0xF, 0xF, false); v = umin2(v, t); // row_shr:1
  t = (u32)__builtin_amdgcn_update_dpp((int)v, (int)v, 0x112, 0xF, 0xF, false); v = umin2(v, t); // row_shr:2
  t = (u32)__builtin_amdgcn_update_dpp((int)v, (int)v, 0x114, 0xF, 0xF, false); v = umin2(v, t); // row_shr:4
  t = (u32)__builtin_amdgcn_update_dpp((int)v, (int)v, 0x118, 0xF, 0xF, false); v = umin2(v, t); // row_shr:8
  t = (u32)__builtin_amdgcn_update_dpp((int)v, (int)v, 0x142, 0xF, 0xF, false); v = umin2(v, t); // row_bcast:15
  t = (u32)__builtin_amdgcn_update_dpp((int)v, (int)v, 0x143, 0xF, 0xF, false); v = umin2(v, t); // row_bcast:31
  return (u32)__builtin_amdgcn_readlane((int)v, 63);
}
// async global->LDS DMA, 16B per lane; LDS dest = wave-uniform base + lane*16
// (layout here is linear in tid, which matches exactly).
__device__ __forceinline__ void lds_cp16(float4* lds_dst, const float4* gsrc) {
  __builtin_amdgcn_global_load_lds(
      (const __attribute__((address_space(1))) unsigned int*)(const void*)gsrc,
      (__attribute__((address_space(3))) unsigned int*)(void*)lds_dst, 16, 0, 0);
}

// ---------- fold1: G = Wg2@Wg1 (64x64); M = Wt2@Wt1 (64x3, row + colT) ----
__global__ __launch_bounds__(256) void fold1_k(
    const float* __restrict__ wg1, const float* __restrict__ wg2,
    const float* __restrict__ wt1, const float* __restrict__ wt2,
    float* __restrict__ G, float* __restrict__ Mrow, float* __restrict__ McT) {
  int t = blockIdx.x * 256 + threadIdx.x;
  if (t < 4096) {
    int o = t >> 6, c = t & 63;
    float acc = 0.f;
    for (int cp = 0; cp < 64; ++cp) acc = fmaf(wg2[o * 64 + cp], wg1[cp * 64 + c], acc);
    G[o * 64 + c] = acc;
  } else if (t < 4096 + 192) {
    int i = t - 4096;
    int o = i / 3, j = i - o * 3;
    float acc = 0.f;
    for (int c = 0; c < 64; ++c) acc = fmaf(wt2[o * 64 + c], wt1[c * 3 + j], acc);
    Mrow[o * 3 + j] = acc;
    McT[j * 64 + o] = acc;
  }
}

// ---------- fold2: GF (G) + WF (wcomb, 192 rows) as bf16 MFMA A-frags -----
// frag layout (16x16x32 A): element (m = lane&15, k = (lane>>4)*8 + j)
__global__ __launch_bounds__(256) void fold2_k(
    const float* __restrict__ G, const float* __restrict__ wl,
    u16* __restrict__ GF, u16* __restrict__ WF) {
  int t = blockIdx.x * 256 + threadIdx.x;  // 16384
  if (t < 12288) {
    int o = t >> 6, c = t & 63;
    float acc = 0.f;
    if (o < 64) {
      for (int cp = 0; cp < 64; ++cp) acc = fmaf(G[o * 64 + cp], wl[cp * 64 + c], acc);
    } else if (o < 128) {
      for (int cp = 0; cp < 64; ++cp) acc = fmaf(G[(o - 64) * 64 + cp], wl[(64 + cp) * 64 + c], acc);
    } else {
      acc = wl[o * 64 + c];
    }
    int ot = o >> 4, m = o & 15;
    int kh = c >> 5, q = (c >> 3) & 3, j = c & 7;
    WF[(((ot * 2 + kh) * 64) + (q * 16 + m)) * 8 + j] = f2bf(acc);
  } else {
    int i = t - 12288;
    int o = i >> 6, c = i & 63;
    int ot = o >> 4, m = o & 15;
    int kh = c >> 5, q = (c >> 3) & 3, j = c & 7;
    GF[(((ot * 2 + kh) * 64) + (q * 16 + m)) * 8 + j] = f2bf(G[o * 64 + c]);
  }
}

// ---------- pack coords as float4 (x,y,z,sq) with NP-EXACT sq -------------
__global__ __launch_bounds__(256) void pack_k(const float* __restrict__ coords,
                                              float4* __restrict__ pack) {
  int g = blockIdx.x * 256 + threadIdx.x;  // 32768
  int b = g >> 13, n = g & (NPT - 1);
  const float* c = coords + (size_t)b * 3 * NPT;
  float x = c[n], y = c[NPT + n], z = c[2 * NPT + n];
  float sq = __fadd_rn(__fadd_rn(__fmul_rn(x, x), __fmul_rn(y, y)), __fmul_rn(z, z));
  pack[g] = make_float4(x, y, z, sq);
}

// ---------- KNN v7c: wave = 4 queries, dbuf DMA staging, C-clamp insert ---
#define QW 4
#define CHUNK 1024
#define NQ 32768
__global__ __launch_bounds__(512, 2) void knn_k(const float4* __restrict__ pack,
                                                u32* __restrict__ part) {
  __shared__ float4 C[2][CHUNK];  // 32 KB
  int tid = threadIdx.x;
  int w = tid >> 6, lane = tid & 63;
  int q0 = blockIdx.x * 32 + w * QW;  // grid 1024 x 8 waves x 4 q = 32768
  int b = q0 >> 13, n0 = q0 & (NPT - 1);
  const float4* pk = pack + (size_t)b * NPT;
  // wave-uniform query coords -> SGPRs (each v_fma may read 1 SGPR)
  float qx[QW], qy[QW], qz[QW], qs[QW];
#pragma unroll
  for (int j = 0; j < QW; ++j) {
    float4 qv = pk[n0 + j];
    qx[j] = rfl_f(qv.x); qy[j] = rfl_f(qv.y);
    qz[j] = rfl_f(qv.z); qs[j] = rfl_f(qv.w);
  }
  u32 arr[QW][8];
#pragma unroll
  for (int j = 0; j < QW; ++j)
#pragma unroll
    for (int s = 0; s < 8; ++s) arr[j][s] = 0xFFFFFFFFu;
  // prologue: stage chunk 0 into C[0]
  lds_cp16(&C[0][tid], pk + tid);
  lds_cp16(&C[0][512 + tid], pk + 512 + tid);
  __syncthreads();  // implicit vmcnt(0) drains the DMA
  for (int c0 = 0; c0 < NPT; c0 += CHUNK) {
    int cur = (c0 >> 10) & 1;
    if (c0 + CHUNK < NPT) {  // issue next-chunk DMA; overlaps compute below
      lds_cp16(&C[cur ^ 1][tid], pk + (c0 + CHUNK) + tid);
      lds_cp16(&C[cur ^ 1][512 + tid], pk + (c0 + CHUNK) + 512 + tid);
    }
#pragma unroll 2
    for (int t = 0; t < CHUNK / 64; ++t) {
      float4 c4 = C[cur][t * 64 + lane];
      u32 ib = (u32)(c0 + t * 64) + (u32)lane;  // s_add folded + v_add
#pragma unroll
      for (int j = 0; j < QW; ++j) {
        float dot = fmaf(qz[j], c4.z, fmaf(qy[j], c4.y, qx[j] * c4.x));
        float d2 = fmaxf(fmaf(-2.f, dot, qs[j] + c4.w), 0.f);
        u32 key = (__float_as_uint(d2) & 0xFFFFE000u) + ib;
        // Sorted-ascending invariant: med3(key, a[i-1], a[i]) ==
        // min(max(key, a[i-1]), a[i]). Pure C -> regalloc-visible
        // (no asm mov bloat); LLVM fuses clamp -> v_med3_u32.
        // Top-down update keeps old neighbor values live. Idempotent
        // for key >= arr[7] -> unconditional, no branch.
        arr[j][7] = umin2(umax2(key, arr[j][6]), arr[j][7]);
        arr[j][6] = umin2(umax2(key, arr[j][5]), arr[j][6]);
        arr[j][5] = umin2(umax2(key, arr[j][4]), arr[j][5]);
        arr[j][4] = umin2(umax2(key, arr[j][3]), arr[j][4]);
        arr[j][3] = umin2(umax2(key, arr[j][2]), arr[j][3]);
        arr[j][2] = umin2(umax2(key, arr[j][1]), arr[j][2]);
        arr[j][1] = umin2(umax2(key, arr[j][0]), arr[j][1]);
        arr[j][0] = umin2(arr[j][0], key);
      }
    }
    __syncthreads();  // readers done + next-chunk DMA drained (vmcnt(0))
  }
  // DPP merge per query: pop global min 24 times (keys unique -> one owner)
#pragma unroll
  for (int j = 0; j < QW; ++j) {
    u32 mg = 0xFFFFFFFFu;
#pragma unroll 1
    for (int r = 0; r < 24; ++r) {
      u32 m = wave_min_u32(arr[j][0]);
      if (lane == r) mg = m;
      if (arr[j][0] == m) {  // owner pops its sorted head
        arr[j][0] = arr[j][1]; arr[j][1] = arr[j][2];
        arr[j][2] = arr[j][3]; arr[j][3] = arr[j][4];
        arr[j][4] = arr[j][5]; arr[j][5] = arr[j][6];
        arr[j][6] = arr[j][7]; arr[j][7] = 0xFFFFFFFFu;
      }
    }
    if (lane < 24) part[(size_t)lane * NQ + q0 + j] = mg;
  }
}

// ---------- numpy-fp32-bit-exact re-rank of the 24 survivors --------------
__global__ __launch_bounds__(64) void refine_k(const float4* __restrict__ pack,
                                               const u32* __restrict__ part,
                                               int* __restrict__ idxk) {
  int g = blockIdx.x * 64 + threadIdx.x;  // 32768
  int b = g >> 13;
  const float4* pk = pack + (size_t)b * NPT;
  float4 q = pk[g & (NPT - 1)];
  float qx = q.x, qy = q.y, qz = q.z, qs = q.w;
  float bd[16];
  int bi[16];
#pragma unroll
  for (int j = 0; j < 16; ++j) { bd[j] = 1e30f; bi[j] = 0x7FFFFFFF; }
#pragma unroll 4
  for (int j = 0; j < 24; ++j) {
    int m = (int)(part[(size_t)j * NQ + g] & 0x1FFFu);
    float4 pm = pk[m];
    float dot = __fadd_rn(__fadd_rn(__fmul_rn(qx, pm.x), __fmul_rn(qy, pm.y)),
                          __fmul_rn(qz, pm.z));
    float kd = __fsub_rn(__fadd_rn(qs, pm.w), __fmul_rn(2.0f, dot));
    int ki = m;
    if (kd < bd[15] || (kd == bd[15] && ki < bi[15])) {
#pragma unroll
      for (int qq = 0; qq < 16; ++qq) {
        bool cs = (kd < bd[qq]) || (kd == bd[qq] && ki < bi[qq]);
        float td = bd[qq];
        int ti = bi[qq];
        bd[qq] = cs ? kd : td;
        bi[qq] = cs ? ki : ti;
        kd = cs ? td : kd;
        ki = cs ? ti : ki;
      }
    }
  }
#pragma unroll
  for (int j = 0; j < 16; ++j) idxk[(size_t)g * 16 + j] = bi[j];
}

// ---------- feat v2 (MFMA): [192x64]@[64x32768] -> featA fp32 / featB bf16
// Wave = 16 points (one B-tile); B[k=kh*32+quad*8+j][col=point] from
// features (64B-coalesced, bf16-packed); 12 o-tiles x 2 MFMA; epilogue
// writes rows 0-63 fp32 (featA) / 64-191 bf16 (featB).
__global__ __launch_bounds__(256) void feat_k(const float* __restrict__ features,
                                              const u16* __restrict__ WF,
                                              float* __restrict__ featA,
                                              u16* __restrict__ featB) {
  int tid = threadIdx.x;
  int w = tid >> 6, l = tid & 63;
  int quad = l >> 4, col = l & 15;
  int P = blockIdx.x * 64 + w * 16 + col;  // grid 512 x 4 waves x 16 pts
  int b = P >> 13, n = P & (NPT - 1);
  const float* fb = features + (size_t)b * 64 * NPT + n;
  const bf8_t* wfr = (const bf8_t*)WF;
  bf8_t Bf[2];
#pragma unroll
  for (int kh = 0; kh < 2; ++kh) {
    union { u32 wv[4]; bf8_t v; } ub;
#pragma unroll
    for (int j2 = 0; j2 < 4; ++j2) {
      float lo = fb[(size_t)(kh * 32 + quad * 8 + j2 * 2) * NPT];
      float hi = fb[(size_t)(kh * 32 + quad * 8 + j2 * 2 + 1) * NPT];
      ub.wv[j2] = pkbf(lo, hi);
    }
    Bf[kh] = ub.v;
  }
#pragma unroll
  for (int ot = 0; ot < 12; ++ot) {
    bf8_t A0 = wfr[(ot * 2 + 0) * 64 + l];
    bf8_t A1 = wfr[(ot * 2 + 1) * 64 + l];
    f32x4 acc = {0.f, 0.f, 0.f, 0.f};
    acc = __builtin_amdgcn_mfma_f32_16x16x32_bf16(A0, Bf[0], acc, 0, 0, 0);
    acc = __builtin_amdgcn_mfma_f32_16x16x32_bf16(A1, Bf[1], acc, 0, 0, 0);
    int gr = ot * 16 + quad * 4;  // C/D: col=lane&15, row=quad*4+reg
    if (ot < 4) {
      *(float4*)(featA + (size_t)P * 64 + gr) = make_float4(acc[0], acc[1], acc[2], acc[3]);
    } else {
      uint2 wv2 = make_uint2(pkbf(acc[0], acc[1]), pkbf(acc[2], acc[3]));
      *(uint2*)(featB + (size_t)P * 128 + (gr - 64)) = wv2;
    }
  }
}

// ---------- attention v3: MFMA core + uniform-gather read phase -----------
#define SROW 68
__global__ __launch_bounds__(64) void attn_k(
    const float4* __restrict__ pack, const int* __restrict__ idxk,
    const float* __restrict__ featA, const u16* __restrict__ featB,
    const u16* __restrict__ GF, const float* __restrict__ Mrow,
    const float* __restrict__ McT, float* __restrict__ out) {
  __shared__ u16 S16[64 * SROW];
  int l = threadIdx.x;
  int quad = l >> 4, col = l & 15;
  int Pb = blockIdx.x * 4;
  int b = Pb >> 13;
  int nb0 = Pb & (NPT - 1);
  const float4* pkb = pack + (size_t)b * NPT;
  int idxv = idxk[(size_t)Pb * 16 + l];  // lane l = (point l>>4, nbr l&15)
  int mve[4];
#pragma unroll
  for (int t = 0; t < 4; ++t) mve[t] = __shfl(idxv, t * 16 + col);
  float relx[4], rely[4], relz[4];
#pragma unroll
  for (int t = 0; t < 4; ++t) {
    float4 own = pkb[nb0 + t];
    float4 nbr = pkb[mve[t]];
    relx[t] = own.x - nbr.x; rely[t] = own.y - nbr.y; relz[t] = own.z - nbr.z;
  }
  // B-frags: u[k=kh*32+quad*8+j][p'=pt*16+col] = relu(M.rel), bf16
  bf8_t Bf[4][2];
#pragma unroll
  for (int kh = 0; kh < 2; ++kh) {
    const float* mr = Mrow + (kh * 32 + quad * 8) * 3;
    float m_[24];
#pragma unroll
    for (int i6 = 0; i6 < 6; ++i6) {
      float4 v = *(const float4*)(mr + i6 * 4);
      m_[i6 * 4] = v.x; m_[i6 * 4 + 1] = v.y; m_[i6 * 4 + 2] = v.z; m_[i6 * 4 + 3] = v.w;
    }
#pragma unroll
    for (int t = 0; t < 4; ++t) {
      float u_[8];
#pragma unroll
      for (int j = 0; j < 8; ++j)
        u_[j] = fmaxf(fmaf(m_[j * 3 + 2], relz[t],
                           fmaf(m_[j * 3 + 1], rely[t], m_[j * 3] * relx[t])), 0.f);
      union { u32 w[4]; bf8_t v; } ub;
#pragma unroll
      for (int j2 = 0; j2 < 4; ++j2) ub.w[j2] = pkbf(u_[j2 * 2], u_[j2 * 2 + 1]);
      Bf[t][kh] = ub.v;
    }
  }
  // MFMA + fused epilogue -> g (bf16) strip [pair][channel]
  const bf8_t* gfr = (const bf8_t*)GF;
#pragma unroll
  for (int ot = 0; ot < 4; ++ot) {
    bf8_t A0 = gfr[(ot * 2 + 0) * 64 + l];
    bf8_t A1 = gfr[(ot * 2 + 1) * 64 + l];
#pragma unroll
    for (int pt = 0; pt < 4; ++pt) {
      f32x4 acc = {0.f, 0.f, 0.f, 0.f};
      acc = __builtin_amdgcn_mfma_f32_16x16x32_bf16(A0, Bf[pt][0], acc, 0, 0, 0);
      acc = __builtin_amdgcn_mfma_f32_16x16x32_bf16(A1, Bf[pt][1], acc, 0, 0, 0);
      const float* phn = featA + (size_t)(Pb + pt) * 64 + ot * 16 + quad * 4;
      float4 ph = *(const float4*)phn;
      uint2 psw = *(const uint2*)(featB + ((size_t)b * NPT + mve[pt]) * 128 + ot * 16 + quad * 4);
      float g0 = fmaxf(acc[0] + ph.x - bf2f((u16)(psw.x & 0xFFFF)), 0.f);
      float g1 = fmaxf(acc[1] + ph.y - bf2f((u16)(psw.x >> 16)), 0.f);
      float g2 = fmaxf(acc[2] + ph.z - bf2f((u16)(psw.y & 0xFFFF)), 0.f);
      float g3 = fmaxf(acc[3] + ph.w - bf2f((u16)(psw.y >> 16)), 0.f);
      uint2 wv = make_uint2(pkbf(g0, g1), pkbf(g2, g3));
      *(uint2*)&S16[(pt * 16 + col) * SROW + ot * 16 + quad * 4] = wv;
    }
  }
  __syncthreads();  // publish g strip (single-wave block: waitcnt fence)
  // read phase v3: lane = channel; pj loop; neighbor idx via readlane
  float mc0 = McT[l], mc1 = McT[64 + l], mc2 = McT[128 + l];
  float accv[4];
#pragma unroll 1
  for (int pj = 0; pj < 4; ++pj) {
    float4 ownq = pkb[nb0 + pj];  // uniform -> scalar path
    float gvv[16];
    float mx = -1e30f;
#pragma unroll
    for (int r = 0; r < 16; ++r) {
      gvv[r] = bf2f(S16[(pj * 16 + r) * SROW + l]);  // 128B coalesced
      mx = fmaxf(mx, gvv[r]);
    }
    float s = 0.f;
#pragma unroll
    for (int r = 0; r < 16; ++r) {
      float e = __expf(gvv[r] - mx);
      gvv[r] = e;
      s += e;
    }
    float inv = 1.0f / s;
    float acc = 0.f;
#pragma unroll
    for (int r = 0; r < 16; ++r) {
      int si = __builtin_amdgcn_readlane(idxv, pj * 16 + r);  // SGPR uniform
      float dl = fmaxf(fmaf(mc2, ownq.z - pkb[si].z,
                            fmaf(mc1, ownq.y - pkb[si].y, mc0 * (ownq.x - pkb[si].x))), 0.f);
      float al = bf2f(featB[((size_t)b * NPT + si) * 128 + 64 + l]);  // 128B coalesced
      acc = fmaf(gvv[r] * inv, al + dl, acc);
    }
    accv[pj] = acc;
  }
  *(float4*)(out + ((size_t)b * 64 + l) * NPT + nb0) =
      make_float4(accv[0], accv[1], accv[2], accv[3]);
}

extern "C" void kernel_launch(void* const* d_in, const int* in_sizes, int n_in,
                              void* d_out, int out_size, void* d_ws, size_t ws_size,
                              hipStream_t stream) {
  const float* features = (const float*)d_in[0];
  const float* coords = (const float*)d_in[1];
  const float* w_lin = (const float*)d_in[2];
  const float* w_t1 = (const float*)d_in[3];
  const float* w_t2 = (const float*)d_in[4];
  const float* w_g1 = (const float*)d_in[5];
  const float* w_g2 = (const float*)d_in[6];
  float* out = (float*)d_out;
  char* ws = (char*)d_ws;
  // workspace layout (~19.5 MB; part overlaps featA, consumed by refine)
  float4* pack = (float4*)ws;                   // 524288 B
  float* G = (float*)(ws + 524288);             // 16384 B
  float* Mrow = (float*)(ws + 540672);          // 768 B
  float* McT = (float*)(ws + 541440);           // 768 B
  int* idxk = (int*)(ws + 591360);              // 2 MB
  float* featA = (float*)(ws + 2688512);        // 8 MB fp32 Gphi
  u16* featB = (u16*)(ws + 11077120);           // 8 MB bf16 Gpsi|alpha
  u32* part = (u32*)(ws + 2688512);             // 3 MB (overlap, freed by refine)
  u16* GF = (u16*)(ws + 19465728);              // 8 KB bf16 G A-frags
  u16* WF = (u16*)(ws + 19473920);              // 24 KB bf16 wcomb A-frags

  fold1_k<<<17, 256, 0, stream>>>(w_g1, w_g2, w_t1, w_t2, G, Mrow, McT);
  fold2_k<<<64, 256, 0, stream>>>(G, w_lin, GF, WF);
  pack_k<<<128, 256, 0, stream>>>(coords, pack);
  knn_k<<<1024, 512, 0, stream>>>(pack, part);
  refine_k<<<512, 64, 0, stream>>>(pack, part, idxk);
  feat_k<<<512, 256, 0, stream>>>(features, WF, featA, featB);  // reuses part region
  attn_k<<<8192, 64, 0, stream>>>(pack, idxk, featA, featB, GF, Mrow, McT, out);
}

// Round 7
// 276.021 us; speedup vs baseline: 1.1659x; 1.1659x over previous
//
#include <hip/hip_runtime.h>
#include <cstdint>

// PointTransformerLayer, MI355X. Folded-weight formulation:
//   M  = Wt2@Wt1 (64x3)          delta = relu(M . rel)
//   G  = Wg2@Wg1 (64x64)         g = relu(Gphi[n] - Gpsi[idx] + G.delta)
//   wcomb rows: [0:64)=G@W1 (phi), [64:128)=G@W2 (psi), [128:192)=Wlin (alpha)
// R19: knn v7d — revert R18 (C minmax did NOT fuse to med3; 141->191 regression)
//   back to asm med3 (R16/R17 form), plus ONE new variable: pin all 32 arr
//   elements to ARCH VGPRs via a zero-instruction empty asm ("+v" x32) inside
//   the t-loop. Evidence: measured slots/iter = 2.2x static VALU consistently
//   (R16 147 vs 67, R18 200 vs 95) AND VGPR_Count 28-32 < live set >=48 with
//   no scratch traffic => allocator parks arr in AGPRs (unified file) and
//   shuttles via v_accvgpr_read/write = real VALU ops ~= the entire gap.
//   launch_bounds (R17) could not test this: it doesn't steer the VGPR/AGPR
//   split. The "v" constraint does.
// R16: QW=4 — amortize each candidate ds_read over 4 queries/wave.
// R12: feat_k MFMA GEMM ([192x64]@[64x32768], fused fp32/bf16 epilogue).

#define NPT 8192
typedef unsigned long long u64;
typedef unsigned int u32;
typedef unsigned short u16;
typedef __attribute__((ext_vector_type(8))) short bf8_t;  // 8 bf16 (4 VGPR)
typedef __attribute__((ext_vector_type(4))) float f32x4;

__device__ __forceinline__ u16 f2bf(float x) {  // round-half-up bf16
  return (u16)((__float_as_uint(x) + 0x8000u) >> 16);
}
__device__ __forceinline__ u32 pkbf(float lo, float hi) {
  return (u32)f2bf(lo) | ((u32)f2bf(hi) << 16);
}
__device__ __forceinline__ float bf2f(u16 v) {
  return __uint_as_float((u32)v << 16);
}
__device__ __forceinline__ u32 med3u(u32 a, u32 b, u32 c) {
  u32 d;
  asm("v_med3_u32 %0, %1, %2, %3" : "=v"(d) : "v"(a), "v"(b), "v"(c));
  return d;
}
__device__ __forceinline__ u32 umin2(u32 a, u32 b) { return a < b ? a : b; }
__device__ __forceinline__ float rfl_f(float x) {  // wave-uniform -> SGPR
  return __uint_as_float((u32)__builtin_amdgcn_readfirstlane((int)__float_as_uint(x)));
}
// full-wave u32 min via DPP (VALU pipe); uniform result via readlane.
__device__ __forceinline__ u32 wave_min_u32(u32 v) {
  u32 t;
  t = (u32)__builtin_amdgcn_update_dpp((int)v, (int)v, 0x111, 0xF, 0xF, false); v = umin2(v, t); // row_shr:1
  t = (u32)__builtin_amdgcn_update_dpp((int)v, (int)v, 0x112, 0xF, 0xF, false); v = umin2(v, t); // row_shr:2
  t = (u32)__builtin_amdgcn_update_dpp((int)v, (int)v, 0x114, 0xF, 0xF, false); v = umin2(v, t); // row_shr:4
  t = (u32)__builtin_amdgcn_update_dpp((int)v, (int)v, 0x118, 0xF, 0xF, false); v = umin2(v, t); // row_shr:8
  t = (u32)__builtin_amdgcn_update_dpp((int)v, (int)v, 0x142, 0xF, 0xF, false); v = umin2(v, t); // row_bcast:15
  t = (u32)__builtin_amdgcn_update_dpp((int)v, (int)v, 0x143, 0xF, 0xF, false); v = umin2(v, t); // row_bcast:31
  return (u32)__builtin_amdgcn_readlane((int)v, 63);
}
// async global->LDS DMA, 16B per lane; LDS dest = wave-uniform base + lane*16
// (layout here is linear in tid, which matches exactly).
__device__ __forceinline__ void lds_cp16(float4* lds_dst, const float4* gsrc) {
  __builtin_amdgcn_global_load_lds(
      (const __attribute__((address_space(1))) unsigned int*)(const void*)gsrc,
      (__attribute__((address_space(3))) unsigned int*)(void*)lds_dst, 16, 0, 0);
}

// ---------- fold1: G = Wg2@Wg1 (64x64); M = Wt2@Wt1 (64x3, row + colT) ----
__global__ __launch_bounds__(256) void fold1_k(
    const float* __restrict__ wg1, const float* __restrict__ wg2,
    const float* __restrict__ wt1, const float* __restrict__ wt2,
    float* __restrict__ G, float* __restrict__ Mrow, float* __restrict__ McT) {
  int t = blockIdx.x * 256 + threadIdx.x;
  if (t < 4096) {
    int o = t >> 6, c = t & 63;
    float acc = 0.f;
    for (int cp = 0; cp < 64; ++cp) acc = fmaf(wg2[o * 64 + cp], wg1[cp * 64 + c], acc);
    G[o * 64 + c] = acc;
  } else if (t < 4096 + 192) {
    int i = t - 4096;
    int o = i / 3, j = i - o * 3;
    float acc = 0.f;
    for (int c = 0; c < 64; ++c) acc = fmaf(wt2[o * 64 + c], wt1[c * 3 + j], acc);
    Mrow[o * 3 + j] = acc;
    McT[j * 64 + o] = acc;
  }
}

// ---------- fold2: GF (G) + WF (wcomb, 192 rows) as bf16 MFMA A-frags -----
// frag layout (16x16x32 A): element (m = lane&15, k = (lane>>4)*8 + j)
__global__ __launch_bounds__(256) void fold2_k(
    const float* __restrict__ G, const float* __restrict__ wl,
    u16* __restrict__ GF, u16* __restrict__ WF) {
  int t = blockIdx.x * 256 + threadIdx.x;  // 16384
  if (t < 12288) {
    int o = t >> 6, c = t & 63;
    float acc = 0.f;
    if (o < 64) {
      for (int cp = 0; cp < 64; ++cp) acc = fmaf(G[o * 64 + cp], wl[cp * 64 + c], acc);
    } else if (o < 128) {
      for (int cp = 0; cp < 64; ++cp) acc = fmaf(G[(o - 64) * 64 + cp], wl[(64 + cp) * 64 + c], acc);
    } else {
      acc = wl[o * 64 + c];
    }
    int ot = o >> 4, m = o & 15;
    int kh = c >> 5, q = (c >> 3) & 3, j = c & 7;
    WF[(((ot * 2 + kh) * 64) + (q * 16 + m)) * 8 + j] = f2bf(acc);
  } else {
    int i = t - 12288;
    int o = i >> 6, c = i & 63;
    int ot = o >> 4, m = o & 15;
    int kh = c >> 5, q = (c >> 3) & 3, j = c & 7;
    GF[(((ot * 2 + kh) * 64) + (q * 16 + m)) * 8 + j] = f2bf(G[o * 64 + c]);
  }
}

// ---------- pack coords as float4 (x,y,z,sq) with NP-EXACT sq -------------
__global__ __launch_bounds__(256) void pack_k(const float* __restrict__ coords,
                                              float4* __restrict__ pack) {
  int g = blockIdx.x * 256 + threadIdx.x;  // 32768
  int b = g >> 13, n = g & (NPT - 1);
  const float* c = coords + (size_t)b * 3 * NPT;
  float x = c[n], y = c[NPT + n], z = c[2 * NPT + n];
  float sq = __fadd_rn(__fadd_rn(__fmul_rn(x, x), __fmul_rn(y, y)), __fmul_rn(z, z));
  pack[g] = make_float4(x, y, z, sq);
}

// ---------- KNN v7d: wave = 4 queries, asm med3, arr pinned to arch VGPRs -
#define QW 4
#define CHUNK 1024
#define NQ 32768
__global__ __launch_bounds__(512, 2) void knn_k(const float4* __restrict__ pack,
                                                u32* __restrict__ part) {
  __shared__ float4 C[2][CHUNK];  // 32 KB
  int tid = threadIdx.x;
  int w = tid >> 6, lane = tid & 63;
  int q0 = blockIdx.x * 32 + w * QW;  // grid 1024 x 8 waves x 4 q = 32768
  int b = q0 >> 13, n0 = q0 & (NPT - 1);
  const float4* pk = pack + (size_t)b * NPT;
  // wave-uniform query coords -> SGPRs (each v_fma may read 1 SGPR)
  float qx[QW], qy[QW], qz[QW], qs[QW];
#pragma unroll
  for (int j = 0; j < QW; ++j) {
    float4 qv = pk[n0 + j];
    qx[j] = rfl_f(qv.x); qy[j] = rfl_f(qv.y);
    qz[j] = rfl_f(qv.z); qs[j] = rfl_f(qv.w);
  }
  u32 arr[QW][8];
#pragma unroll
  for (int j = 0; j < QW; ++j)
#pragma unroll
    for (int s = 0; s < 8; ++s) arr[j][s] = 0xFFFFFFFFu;
  // prologue: stage chunk 0 into C[0]
  lds_cp16(&C[0][tid], pk + tid);
  lds_cp16(&C[0][512 + tid], pk + 512 + tid);
  __syncthreads();  // implicit vmcnt(0) drains the DMA
  for (int c0 = 0; c0 < NPT; c0 += CHUNK) {
    int cur = (c0 >> 10) & 1;
    if (c0 + CHUNK < NPT) {  // issue next-chunk DMA; overlaps compute below
      lds_cp16(&C[cur ^ 1][tid], pk + (c0 + CHUNK) + tid);
      lds_cp16(&C[cur ^ 1][512 + tid], pk + (c0 + CHUNK) + 512 + tid);
    }
#pragma unroll 2
    for (int t = 0; t < CHUNK / 64; ++t) {
      float4 c4 = C[cur][t * 64 + lane];
      u32 ib = (u32)(c0 + t * 64) + (u32)lane;  // s_add folded + v_add
#pragma unroll
      for (int j = 0; j < QW; ++j) {
        float dot = fmaf(qz[j], c4.z, fmaf(qy[j], c4.y, qx[j] * c4.x));
        float d2 = fmaxf(fmaf(-2.f, dot, qs[j] + c4.w), 0.f);
        u32 key = (__float_as_uint(d2) & 0xFFFFE000u) + ib;
        // UNCONDITIONAL sorted-insert-drop-max: idempotent when key>=arr[7]
        arr[j][7] = med3u(key, arr[j][6], arr[j][7]);
        arr[j][6] = med3u(key, arr[j][5], arr[j][6]);
        arr[j][5] = med3u(key, arr[j][4], arr[j][5]);
        arr[j][4] = med3u(key, arr[j][3], arr[j][4]);
        arr[j][3] = med3u(key, arr[j][2], arr[j][3]);
        arr[j][2] = med3u(key, arr[j][1], arr[j][2]);
        arr[j][1] = med3u(key, arr[j][0], arr[j][1]);
        arr[j][0] = umin2(arr[j][0], key);
      }
      // R19: pin the whole top-8 state into ARCH VGPRs ("v" class) at every
      // iteration boundary. Zero instructions; defeats the allocator's
      // AGPR-parking (v_accvgpr_read/write shuttle = the 2.2x phantom ops).
      asm volatile("" :
        "+v"(arr[0][0]), "+v"(arr[0][1]), "+v"(arr[0][2]), "+v"(arr[0][3]),
        "+v"(arr[0][4]), "+v"(arr[0][5]), "+v"(arr[0][6]), "+v"(arr[0][7]),
        "+v"(arr[1][0]), "+v"(arr[1][1]), "+v"(arr[1][2]), "+v"(arr[1][3]),
        "+v"(arr[1][4]), "+v"(arr[1][5]), "+v"(arr[1][6]), "+v"(arr[1][7]),
        "+v"(arr[2][0]), "+v"(arr[2][1]), "+v"(arr[2][2]), "+v"(arr[2][3]),
        "+v"(arr[2][4]), "+v"(arr[2][5]), "+v"(arr[2][6]), "+v"(arr[2][7]),
        "+v"(arr[3][0]), "+v"(arr[3][1]), "+v"(arr[3][2]), "+v"(arr[3][3]),
        "+v"(arr[3][4]), "+v"(arr[3][5]), "+v"(arr[3][6]), "+v"(arr[3][7]));
    }
    __syncthreads();  // readers done + next-chunk DMA drained (vmcnt(0))
  }
  // DPP merge per query: pop global min 24 times (keys unique -> one owner)
#pragma unroll
  for (int j = 0; j < QW; ++j) {
    u32 mg = 0xFFFFFFFFu;
#pragma unroll 1
    for (int r = 0; r < 24; ++r) {
      u32 m = wave_min_u32(arr[j][0]);
      if (lane == r) mg = m;
      if (arr[j][0] == m) {  // owner pops its sorted head
        arr[j][0] = arr[j][1]; arr[j][1] = arr[j][2];
        arr[j][2] = arr[j][3]; arr[j][3] = arr[j][4];
        arr[j][4] = arr[j][5]; arr[j][5] = arr[j][6];
        arr[j][6] = arr[j][7]; arr[j][7] = 0xFFFFFFFFu;
      }
    }
    if (lane < 24) part[(size_t)lane * NQ + q0 + j] = mg;
  }
}

// ---------- numpy-fp32-bit-exact re-rank of the 24 survivors --------------
__global__ __launch_bounds__(64) void refine_k(const float4* __restrict__ pack,
                                               const u32* __restrict__ part,
                                               int* __restrict__ idxk) {
  int g = blockIdx.x * 64 + threadIdx.x;  // 32768
  int b = g >> 13;
  const float4* pk = pack + (size_t)b * NPT;
  float4 q = pk[g & (NPT - 1)];
  float qx = q.x, qy = q.y, qz = q.z, qs = q.w;
  float bd[16];
  int bi[16];
#pragma unroll
  for (int j = 0; j < 16; ++j) { bd[j] = 1e30f; bi[j] = 0x7FFFFFFF; }
#pragma unroll 4
  for (int j = 0; j < 24; ++j) {
    int m = (int)(part[(size_t)j * NQ + g] & 0x1FFFu);
    float4 pm = pk[m];
    float dot = __fadd_rn(__fadd_rn(__fmul_rn(qx, pm.x), __fmul_rn(qy, pm.y)),
                          __fmul_rn(qz, pm.z));
    float kd = __fsub_rn(__fadd_rn(qs, pm.w), __fmul_rn(2.0f, dot));
    int ki = m;
    if (kd < bd[15] || (kd == bd[15] && ki < bi[15])) {
#pragma unroll
      for (int qq = 0; qq < 16; ++qq) {
        bool cs = (kd < bd[qq]) || (kd == bd[qq] && ki < bi[qq]);
        float td = bd[qq];
        int ti = bi[qq];
        bd[qq] = cs ? kd : td;
        bi[qq] = cs ? ki : ti;
        kd = cs ? td : kd;
        ki = cs ? ti : ki;
      }
    }
  }
#pragma unroll
  for (int j = 0; j < 16; ++j) idxk[(size_t)g * 16 + j] = bi[j];
}

// ---------- feat v2 (MFMA): [192x64]@[64x32768] -> featA fp32 / featB bf16
// Wave = 16 points (one B-tile); B[k=kh*32+quad*8+j][col=point] from
// features (64B-coalesced, bf16-packed); 12 o-tiles x 2 MFMA; epilogue
// writes rows 0-63 fp32 (featA) / 64-191 bf16 (featB).
__global__ __launch_bounds__(256) void feat_k(const float* __restrict__ features,
                                              const u16* __restrict__ WF,
                                              float* __restrict__ featA,
                                              u16* __restrict__ featB) {
  int tid = threadIdx.x;
  int w = tid >> 6, l = tid & 63;
  int quad = l >> 4, col = l & 15;
  int P = blockIdx.x * 64 + w * 16 + col;  // grid 512 x 4 waves x 16 pts
  int b = P >> 13, n = P & (NPT - 1);
  const float* fb = features + (size_t)b * 64 * NPT + n;
  const bf8_t* wfr = (const bf8_t*)WF;
  bf8_t Bf[2];
#pragma unroll
  for (int kh = 0; kh < 2; ++kh) {
    union { u32 wv[4]; bf8_t v; } ub;
#pragma unroll
    for (int j2 = 0; j2 < 4; ++j2) {
      float lo = fb[(size_t)(kh * 32 + quad * 8 + j2 * 2) * NPT];
      float hi = fb[(size_t)(kh * 32 + quad * 8 + j2 * 2 + 1) * NPT];
      ub.wv[j2] = pkbf(lo, hi);
    }
    Bf[kh] = ub.v;
  }
#pragma unroll
  for (int ot = 0; ot < 12; ++ot) {
    bf8_t A0 = wfr[(ot * 2 + 0) * 64 + l];
    bf8_t A1 = wfr[(ot * 2 + 1) * 64 + l];
    f32x4 acc = {0.f, 0.f, 0.f, 0.f};
    acc = __builtin_amdgcn_mfma_f32_16x16x32_bf16(A0, Bf[0], acc, 0, 0, 0);
    acc = __builtin_amdgcn_mfma_f32_16x16x32_bf16(A1, Bf[1], acc, 0, 0, 0);
    int gr = ot * 16 + quad * 4;  // C/D: col=lane&15, row=quad*4+reg
    if (ot < 4) {
      *(float4*)(featA + (size_t)P * 64 + gr) = make_float4(acc[0], acc[1], acc[2], acc[3]);
    } else {
      uint2 wv2 = make_uint2(pkbf(acc[0], acc[1]), pkbf(acc[2], acc[3]));
      *(uint2*)(featB + (size_t)P * 128 + (gr - 64)) = wv2;
    }
  }
}

// ---------- attention v3: MFMA core + uniform-gather read phase -----------
#define SROW 68
__global__ __launch_bounds__(64) void attn_k(
    const float4* __restrict__ pack, const int* __restrict__ idxk,
    const float* __restrict__ featA, const u16* __restrict__ featB,
    const u16* __restrict__ GF, const float* __restrict__ Mrow,
    const float* __restrict__ McT, float* __restrict__ out) {
  __shared__ u16 S16[64 * SROW];
  int l = threadIdx.x;
  int quad = l >> 4, col = l & 15;
  int Pb = blockIdx.x * 4;
  int b = Pb >> 13;
  int nb0 = Pb & (NPT - 1);
  const float4* pkb = pack + (size_t)b * NPT;
  int idxv = idxk[(size_t)Pb * 16 + l];  // lane l = (point l>>4, nbr l&15)
  int mve[4];
#pragma unroll
  for (int t = 0; t < 4; ++t) mve[t] = __shfl(idxv, t * 16 + col);
  float relx[4], rely[4], relz[4];
#pragma unroll
  for (int t = 0; t < 4; ++t) {
    float4 own = pkb[nb0 + t];
    float4 nbr = pkb[mve[t]];
    relx[t] = own.x - nbr.x; rely[t] = own.y - nbr.y; relz[t] = own.z - nbr.z;
  }
  // B-frags: u[k=kh*32+quad*8+j][p'=pt*16+col] = relu(M.rel), bf16
  bf8_t Bf[4][2];
#pragma unroll
  for (int kh = 0; kh < 2; ++kh) {
    const float* mr = Mrow + (kh * 32 + quad * 8) * 3;
    float m_[24];
#pragma unroll
    for (int i6 = 0; i6 < 6; ++i6) {
      float4 v = *(const float4*)(mr + i6 * 4);
      m_[i6 * 4] = v.x; m_[i6 * 4 + 1] = v.y; m_[i6 * 4 + 2] = v.z; m_[i6 * 4 + 3] = v.w;
    }
#pragma unroll
    for (int t = 0; t < 4; ++t) {
      float u_[8];
#pragma unroll
      for (int j = 0; j < 8; ++j)
        u_[j] = fmaxf(fmaf(m_[j * 3 + 2], relz[t],
                           fmaf(m_[j * 3 + 1], rely[t], m_[j * 3] * relx[t])), 0.f);
      union { u32 w[4]; bf8_t v; } ub;
#pragma unroll
      for (int j2 = 0; j2 < 4; ++j2) ub.w[j2] = pkbf(u_[j2 * 2], u_[j2 * 2 + 1]);
      Bf[t][kh] = ub.v;
    }
  }
  // MFMA + fused epilogue -> g (bf16) strip [pair][channel]
  const bf8_t* gfr = (const bf8_t*)GF;
#pragma unroll
  for (int ot = 0; ot < 4; ++ot) {
    bf8_t A0 = gfr[(ot * 2 + 0) * 64 + l];
    bf8_t A1 = gfr[(ot * 2 + 1) * 64 + l];
#pragma unroll
    for (int pt = 0; pt < 4; ++pt) {
      f32x4 acc = {0.f, 0.f, 0.f, 0.f};
      acc = __builtin_amdgcn_mfma_f32_16x16x32_bf16(A0, Bf[pt][0], acc, 0, 0, 0);
      acc = __builtin_amdgcn_mfma_f32_16x16x32_bf16(A1, Bf[pt][1], acc, 0, 0, 0);
      const float* phn = featA + (size_t)(Pb + pt) * 64 + ot * 16 + quad * 4;
      float4 ph = *(const float4*)phn;
      uint2 psw = *(const uint2*)(featB + ((size_t)b * NPT + mve[pt]) * 128 + ot * 16 + quad * 4);
      float g0 = fmaxf(acc[0] + ph.x - bf2f((u16)(psw.x & 0xFFFF)), 0.f);
      float g1 = fmaxf(acc[1] + ph.y - bf2f((u16)(psw.x >> 16)), 0.f);
      float g2 = fmaxf(acc[2] + ph.z - bf2f((u16)(psw.y & 0xFFFF)), 0.f);
      float g3 = fmaxf(acc[3] + ph.w - bf2f((u16)(psw.y >> 16)), 0.f);
      uint2 wv = make_uint2(pkbf(g0, g1), pkbf(g2, g3));
      *(uint2*)&S16[(pt * 16 + col) * SROW + ot * 16 + quad * 4] = wv;
    }
  }
  __syncthreads();  // publish g strip (single-wave block: waitcnt fence)
  // read phase v3: lane = channel; pj loop; neighbor idx via readlane
  float mc0 = McT[l], mc1 = McT[64 + l], mc2 = McT[128 + l];
  float accv[4];
#pragma unroll 1
  for (int pj = 0; pj < 4; ++pj) {
    float4 ownq = pkb[nb0 + pj];  // uniform -> scalar path
    float gvv[16];
    float mx = -1e30f;
#pragma unroll
    for (int r = 0; r < 16; ++r) {
      gvv[r] = bf2f(S16[(pj * 16 + r) * SROW + l]);  // 128B coalesced
      mx = fmaxf(mx, gvv[r]);
    }
    float s = 0.f;
#pragma unroll
    for (int r = 0; r < 16; ++r) {
      float e = __expf(gvv[r] - mx);
      gvv[r] = e;
      s += e;
    }
    float inv = 1.0f / s;
    float acc = 0.f;
#pragma unroll
    for (int r = 0; r < 16; ++r) {
      int si = __builtin_amdgcn_readlane(idxv, pj * 16 + r);  // SGPR uniform
      float dl = fmaxf(fmaf(mc2, ownq.z - pkb[si].z,
                            fmaf(mc1, ownq.y - pkb[si].y, mc0 * (ownq.x - pkb[si].x))), 0.f);
      float al = bf2f(featB[((size_t)b * NPT + si) * 128 + 64 + l]);  // 128B coalesced
      acc = fmaf(gvv[r] * inv, al + dl, acc);
    }
    accv[pj] = acc;
  }
  *(float4*)(out + ((size_t)b * 64 + l) * NPT + nb0) =
      make_float4(accv[0], accv[1], accv[2], accv[3]);
}

extern "C" void kernel_launch(void* const* d_in, const int* in_sizes, int n_in,
                              void* d_out, int out_size, void* d_ws, size_t ws_size,
                              hipStream_t stream) {
  const float* features = (const float*)d_in[0];
  const float* coords = (const float*)d_in[1];
  const float* w_lin = (const float*)d_in[2];
  const float* w_t1 = (const float*)d_in[3];
  const float* w_t2 = (const float*)d_in[4];
  const float* w_g1 = (const float*)d_in[5];
  const float* w_g2 = (const float*)d_in[6];
  float* out = (float*)d_out;
  char* ws = (char*)d_ws;
  // workspace layout (~19.5 MB; part overlaps featA, consumed by refine)
  float4* pack = (float4*)ws;                   // 524288 B
  float* G = (float*)(ws + 524288);             // 16384 B
  float* Mrow = (float*)(ws + 540672);          // 768 B
  float* McT = (float*)(ws + 541440);           // 768 B
  int* idxk = (int*)(ws + 591360);              // 2 MB
  float* featA = (float*)(ws + 2688512);        // 8 MB fp32 Gphi
  u16* featB = (u16*)(ws + 11077120);           // 8 MB bf16 Gpsi|alpha
  u32* part = (u32*)(ws + 2688512);             // 3 MB (overlap, freed by refine)
  u16* GF = (u16*)(ws + 19465728);              // 8 KB bf16 G A-frags
  u16* WF = (u16*)(ws + 19473920);              // 24 KB bf16 wcomb A-frags

  fold1_k<<<17, 256, 0, stream>>>(w_g1, w_g2, w_t1, w_t2, G, Mrow, McT);
  fold2_k<<<64, 256, 0, stream>>>(G, w_lin, GF, WF);
  pack_k<<<128, 256, 0, stream>>>(coords, pack);
  knn_k<<<1024, 512, 0, stream>>>(pack, part);
  refine_k<<<512, 64, 0, stream>>>(pack, part, idxk);
  feat_k<<<512, 256, 0, stream>>>(features, WF, featA, featB);  // reuses part region
  attn_k<<<8192, 64, 0, stream>>>(pack, idxk, featA, featB, GF, Mrow, McT, out);
}